// Round 1
// baseline (504.542 us; speedup 1.0000x reference)
//
#include <hip/hip_runtime.h>

// ConnectivityLoss: fused soft-skeletonize(5 iters) + connectivity MSE.
// One block = one 32x64 output tile of one image, pred AND target both
// processed in LDS with an 11-pixel halo. No workspace needed.

#define IMG  512
#define TH   32
#define TW   64
#define HS   11
#define SH   (TH + 2*HS)   // 54
#define SW   (TW + 2*HS)   // 86
#define NPIX (SH*SW)       // 4644
#define SKH  (TH + 2)      // 34
#define SKW  (TW + 2)      // 66
#define NT   256

__global__ __launch_bounds__(NT)
void skel_conn_loss(const float* __restrict__ pred,
                    const float* __restrict__ target,
                    float* __restrict__ out)
{
    __shared__ float A[NPIX];        // current x (then skeleton)
    __shared__ float B[NPIX];        // minpool scratch
    __shared__ float SKP[SKH*SKW];   // pred skeleton (1-halo region)
    __shared__ float red[NT/64];

    const int tid = threadIdx.x;
    const int img = blockIdx.x >> 7;       // 128 tiles per image
    const int rem = blockIdx.x & 127;
    const int ty0 = (rem >> 3) * TH;       // 16 row-tiles
    const int tx0 = (rem & 7)  * TW;       // 8 col-tiles
    const int oy  = ty0 - HS;              // global row of tile-local row 0
    const int ox  = tx0 - HS;

    // Local-coordinate clamp bounds: image borders AND tile borders in one
    // clamp. Replicate-clamp == ignore-OOB for min/max pooling; positions
    // whose window would need out-of-tile data are garbage but provably
    // outside the valid margin (shrinks 2/side/iter) and never consumed.
    const int cLoY = max(0, -oy);
    const int cHiY = min(SH - 1, (IMG - 1) - oy);
    const int cLoX = max(0, -ox);
    const int cHiX = min(SW - 1, (IMG - 1) - ox);

    for (int t = 0; t < 2; ++t) {
        const float* __restrict__ src =
            (t == 0 ? pred : target) + (size_t)img * (IMG * IMG);

        // ---- load tile (zeros outside image; unused there anyway) ----
        for (int p = tid; p < NPIX; p += NT) {
            int ly = p / SW, lx = p - ly * SW;
            int gy = oy + ly, gx = ox + lx;
            float v = 0.0f;
            if ((unsigned)gy < IMG && (unsigned)gx < IMG)
                v = src[gy * IMG + gx];
            A[p] = v;
        }
        __syncthreads();

        // ---- 5 skeletonize iterations ----
        #pragma unroll 1
        for (int it = 0; it < 5; ++it) {
            // pass 1: B = minpool3(A)  (clamped-window == SAME w/ +inf pad)
            for (int p = tid; p < NPIX; p += NT) {
                int ly = p / SW, lx = p - ly * SW;
                int ym = max(ly - 1, cLoY), yp = min(ly + 1, cHiY);
                int xm = max(lx - 1, cLoX), xp = min(lx + 1, cHiX);
                const float* r0 = A + ym * SW;
                const float* r1 = A + ly * SW;
                const float* r2 = A + yp * SW;
                float m0 = fminf(fminf(r0[xm], r0[lx]), r0[xp]);
                float m1 = fminf(fminf(r1[xm], r1[lx]), r1[xp]);
                float m2 = fminf(fminf(r2[xm], r2[lx]), r2[xp]);
                B[p] = fminf(fminf(m0, m1), m2);
            }
            __syncthreads();
            // pass 2: A = relu(A - relu(maxpool3(B) - B))   (in-place ok:
            // each thread reads only its own A[p] in this pass)
            for (int p = tid; p < NPIX; p += NT) {
                int ly = p / SW, lx = p - ly * SW;
                int ym = max(ly - 1, cLoY), yp = min(ly + 1, cHiY);
                int xm = max(lx - 1, cLoX), xp = min(lx + 1, cHiX);
                const float* r0 = B + ym * SW;
                const float* r1 = B + ly * SW;
                const float* r2 = B + yp * SW;
                float m0 = fmaxf(fmaxf(r0[xm], r0[lx]), r0[xp]);
                float m1 = fmaxf(fmaxf(r1[xm], r1[lx]), r1[xp]);
                float m2 = fmaxf(fmaxf(r2[xm], r2[lx]), r2[xp]);
                float mx = fmaxf(fmaxf(m0, m1), m2);
                float contour = fmaxf(mx - B[p], 0.0f);
                A[p] = fmaxf(A[p] - contour, 0.0f);
            }
            __syncthreads();
        }

        if (t == 0) {
            // stash pred skeleton (valid margin-10 region, 1-halo for sumpool)
            for (int p = tid; p < SKH * SKW; p += NT) {
                int ly = p / SKW, lx = p - ly * SKW;
                SKP[p] = A[(ly + HS - 1) * SW + (lx + HS - 1)];
            }
            __syncthreads();
        }
    }

    // ---- combine: sumpool3 + indicators + weighted squared diff ----
    // A = target skeleton (tile coords), SKP = pred skeleton (offset HS-1)
    float acc = 0.0f;
    for (int p = tid; p < TH * TW; p += NT) {
        int ly = p >> 6, lx = p & 63;   // TW == 64
        int gy = ty0 + ly, gx = tx0 + lx;
        float ps = SKP[(ly + 1) * SKW + (lx + 1)];
        float ts = A[(ly + HS) * SW + (lx + HS)];
        float pn = 0.0f, tn = 0.0f;
        #pragma unroll
        for (int dy = -1; dy <= 1; ++dy) {
            bool yok = (unsigned)(gy + dy) < IMG;
            #pragma unroll
            for (int dx = -1; dx <= 1; ++dx) {
                bool ok = yok && ((unsigned)(gx + dx) < IMG);
                if (ok) {
                    pn += SKP[(ly + 1 + dy) * SKW + (lx + 1 + dx)];
                    tn += A[(ly + HS + dy) * SW + (lx + HS + dx)];
                }
            }
        }
        float pon = (ps > 0.5f) ? 1.0f : 0.0f;
        float ton = (ts > 0.5f) ? 1.0f : 0.0f;
        float pe = (pn == 2.0f) ? pon : 0.0f;
        float te = (tn == 2.0f) ? ton : 0.0f;
        float pc = (pn >= 4.0f) ? pon : 0.0f;
        float tc = (tn >= 4.0f) ? ton : 0.0f;
        float ds = ps - ts, de = pe - te, dc = pc - tc;
        acc += 0.6f * ds * ds + 0.2f * (de * de + dc * dc);
    }

    // ---- block reduction -> single atomic ----
    #pragma unroll
    for (int off = 32; off >= 1; off >>= 1)
        acc += __shfl_down(acc, off, 64);
    if ((tid & 63) == 0) red[tid >> 6] = acc;
    __syncthreads();
    if (tid == 0) {
        float s = red[0] + red[1] + red[2] + red[3];
        atomicAdd(out, s * (1.0f / 8388608.0f));  // N = 32*512*512 = 2^23
    }
}

extern "C" void kernel_launch(void* const* d_in, const int* in_sizes, int n_in,
                              void* d_out, int out_size, void* d_ws, size_t ws_size,
                              hipStream_t stream) {
    const float* pred   = (const float*)d_in[0];
    const float* target = (const float*)d_in[1];
    float* out = (float*)d_out;
    // d_out is poisoned to 0xAA before every timed launch; zero it ourselves.
    hipMemsetAsync(d_out, 0, sizeof(float) * (out_size > 0 ? out_size : 1), stream);
    const int nblocks = 32 * 128;   // 32 images x (16x8) tiles
    skel_conn_loss<<<nblocks, NT, 0, stream>>>(pred, target, out);
}

// Round 2
// 352.083 us; speedup vs baseline: 1.4330x; 1.4330x over previous
//
#include <hip/hip_runtime.h>

// ConnectivityLoss: fused soft-skeletonize(5 iters) + connectivity MSE.
// R2: register-blocked pool passes. Each thread owns a 4-col x 5-row strip;
// replicate-padding (maintained by border fixup) removes all per-pixel
// clamping so every LDS access is base + immediate offset. b128 row reads
// + v_min3/v_max3 trees.

#define IMG  512
#define TH   32
#define TW   64
#define PW   88            // padded row stride (floats); 22 strips of 4
#define PH   58            // rows 0..57; data rows 1..54, compute rows 2..56
#define ASZ  (PH*PW)       // 5104
#define SKH  34
#define SKW  66
#define SKSZ (SKH*SKW)     // 2244
#define NT   256

__device__ __forceinline__ float f3min(float a, float b, float c) {
    return fminf(fminf(a, b), c);
}
__device__ __forceinline__ float f3max(float a, float b, float c) {
    return fmaxf(fmaxf(a, b), c);
}

__global__ __launch_bounds__(NT, 3)
void skel_conn_loss(const float* __restrict__ pred,
                    const float* __restrict__ target,
                    float* __restrict__ out)
{
    __shared__ float lds[2*ASZ + SKSZ];   // A | B | SKP  (49.8 KB)
    __shared__ float red[4];
    float* __restrict__ Aa  = lds;
    float* __restrict__ Bb  = lds + ASZ;
    float* __restrict__ SKP = lds + 2*ASZ;

    const int tid = threadIdx.x;
    const int img = blockIdx.x >> 7;       // 128 tiles per image
    const int rem = blockIdx.x & 127;
    const int ty0 = (rem >> 3) * TH;       // 16 row-tiles
    const int tx0 = (rem & 7)  * TW;       // 8 col-tiles

    // padded (pr,pc) <-> global (ty0-12+pr, tx0-12+pc); data at 1..54 / 1..86
    const bool lB = (tx0 == 0);
    const bool rB = (tx0 + TW + 10 >= IMG);   // only tx0 == 448
    const bool tB = (ty0 == 0);
    const bool bB = (ty0 + TH + 10 >= IMG);   // only ty0 == 480
    const bool anyB = lB | rB | tB | bB;
    const int rfc = 2*IMG - IMG + 12 - tx0 + 0 + (IMG - IMG); // = IMG - tx0 + 12
    const int rfcol = IMG - tx0 + 12;   // col of gx==IMG (used iff rB) -> 76
    const int bfrow = IMG - ty0 + 12;   // row of gy==IMG (used iff bB) -> 44
    (void)rfc;

    // strip assignment: 22 strips x 11 groups of 5 rows (rows 2..56)
    const int s   = tid % 22;
    const int g   = tid / 22;
    const bool act = (g < 11);
    const int r0  = 2 + 5*g;
    const int pc0 = 4*s;
    const int ibR = (r0 - 1)*PW + pc0;   // stencil read base (row r0-1)
    const int ibW = r0*PW + pc0;         // write / center base

    // replicate-line fixup after each pass (image borders only; block-uniform)
    auto fixup = [&](float* __restrict__ X) {
        if (lB) for (int r = tid; r < PH; r += NT) {
            int rs = r;
            if (tB && rs < 12) rs = 12;
            if (bB && rs >= bfrow) rs = bfrow - 1;
            X[r*PW + 11] = X[rs*PW + 12];
        }
        if (rB) for (int r = tid; r < PH; r += NT) {
            int rs = r;
            if (tB && rs < 12) rs = 12;
            if (bB && rs >= bfrow) rs = bfrow - 1;
            X[r*PW + rfcol] = X[rs*PW + rfcol - 1];
        }
        if (tB) for (int c = tid; c < PW; c += NT) {
            int cs = c;
            if (lB && cs < 12) cs = 12;
            if (rB && cs >= rfcol) cs = rfcol - 1;
            X[11*PW + c] = X[12*PW + cs];
        }
        if (bB) for (int c = tid; c < PW; c += NT) {
            int cs = c;
            if (lB && cs < 12) cs = 12;
            if (rB && cs >= rfcol) cs = rfcol - 1;
            X[bfrow*PW + c] = X[(bfrow - 1)*PW + cs];
        }
    };

    for (int t = 0; t < 2; ++t) {
        const float* __restrict__ src =
            (t == 0 ? pred : target) + (size_t)img * (IMG * IMG);

        // ---- replicate-clamped load (handles image-border padding) ----
        for (int p = tid; p < ASZ; p += NT) {
            int pr = p / PW, pc = p - pr * PW;
            int gy = min(max(ty0 - 12 + pr, 0), IMG - 1);
            int gx = min(max(tx0 - 12 + pc, 0), IMG - 1);
            Aa[p] = src[gy * IMG + gx];
        }
        __syncthreads();

        #pragma unroll 1
        for (int it = 0; it < 5; ++it) {
            // ---- pass 1: B = minpool3(A) ----
            if (act) {
                float4 c[7]; float le[7], ri[7];
                #pragma unroll
                for (int k = 0; k < 7; ++k) {
                    c[k]  = *(const float4*)&Aa[ibR + k*PW];
                    le[k] = Aa[ibR + k*PW - 1];
                    ri[k] = Aa[ibR + k*PW + 4];
                }
                float4 h[7];
                #pragma unroll
                for (int k = 0; k < 7; ++k) {
                    h[k].x = f3min(le[k],  c[k].x, c[k].y);
                    h[k].y = f3min(c[k].x, c[k].y, c[k].z);
                    h[k].z = f3min(c[k].y, c[k].z, c[k].w);
                    h[k].w = f3min(c[k].z, c[k].w, ri[k]);
                }
                #pragma unroll
                for (int i = 0; i < 5; ++i) {
                    float4 o;
                    o.x = f3min(h[i].x, h[i+1].x, h[i+2].x);
                    o.y = f3min(h[i].y, h[i+1].y, h[i+2].y);
                    o.z = f3min(h[i].z, h[i+1].z, h[i+2].z);
                    o.w = f3min(h[i].w, h[i+1].w, h[i+2].w);
                    *(float4*)&Bb[ibW + i*PW] = o;
                }
            }
            __syncthreads();
            if (anyB) { fixup(Bb); __syncthreads(); }

            // ---- pass 2: A = relu(A - relu(maxpool3(B) - B)) ----
            if (act) {
                float4 c[7]; float le[7], ri[7];
                #pragma unroll
                for (int k = 0; k < 7; ++k) {
                    c[k]  = *(const float4*)&Bb[ibR + k*PW];
                    le[k] = Bb[ibR + k*PW - 1];
                    ri[k] = Bb[ibR + k*PW + 4];
                }
                float4 h[7];
                #pragma unroll
                for (int k = 0; k < 7; ++k) {
                    h[k].x = f3max(le[k],  c[k].x, c[k].y);
                    h[k].y = f3max(c[k].x, c[k].y, c[k].z);
                    h[k].z = f3max(c[k].y, c[k].z, c[k].w);
                    h[k].w = f3max(c[k].z, c[k].w, ri[k]);
                }
                #pragma unroll
                for (int i = 0; i < 5; ++i) {
                    float4 mx;
                    mx.x = f3max(h[i].x, h[i+1].x, h[i+2].x);
                    mx.y = f3max(h[i].y, h[i+1].y, h[i+2].y);
                    mx.z = f3max(h[i].z, h[i+1].z, h[i+2].z);
                    mx.w = f3max(h[i].w, h[i+1].w, h[i+2].w);
                    float4 bc = c[i+1];          // B center row r0+i
                    float4 a  = *(const float4*)&Aa[ibW + i*PW];
                    a.x = fmaxf(a.x - fmaxf(mx.x - bc.x, 0.f), 0.f);
                    a.y = fmaxf(a.y - fmaxf(mx.y - bc.y, 0.f), 0.f);
                    a.z = fmaxf(a.z - fmaxf(mx.z - bc.z, 0.f), 0.f);
                    a.w = fmaxf(a.w - fmaxf(mx.w - bc.w, 0.f), 0.f);
                    *(float4*)&Aa[ibW + i*PW] = a;
                }
            }
            __syncthreads();
            if (anyB) { fixup(Aa); __syncthreads(); }
        }

        if (t == 0) {
            // stash pred skeleton (margin-1 region) before target reuses A
            for (int p = tid; p < SKSZ; p += NT) {
                int ly = p / SKW, lx = p - ly * SKW;
                SKP[p] = Aa[(ly + 11)*PW + (lx + 11)];
            }
            __syncthreads();
        }
    }

    // ---- epilogue: sumpool3 + indicators + weighted squared diff ----
    float acc = 0.0f;
    for (int p = tid; p < TH * TW; p += NT) {
        int ly = p >> 6, lx = p & 63;   // TW == 64
        int gy = ty0 + ly, gx = tx0 + lx;
        float ps = SKP[(ly + 1)*SKW + (lx + 1)];
        float ts = Aa[(ly + 12)*PW + (lx + 12)];
        float pn = 0.0f, tn = 0.0f;
        #pragma unroll
        for (int dy = -1; dy <= 1; ++dy) {
            bool yok = (unsigned)(gy + dy) < IMG;
            #pragma unroll
            for (int dx = -1; dx <= 1; ++dx) {
                bool ok = yok && ((unsigned)(gx + dx) < IMG);
                if (ok) {
                    pn += SKP[(ly + 1 + dy)*SKW + (lx + 1 + dx)];
                    tn += Aa[(ly + 12 + dy)*PW + (lx + 12 + dx)];
                }
            }
        }
        float pon = (ps > 0.5f) ? 1.0f : 0.0f;
        float ton = (ts > 0.5f) ? 1.0f : 0.0f;
        float pe = (pn == 2.0f) ? pon : 0.0f;
        float te = (tn == 2.0f) ? ton : 0.0f;
        float pc = (pn >= 4.0f) ? pon : 0.0f;
        float tc = (tn >= 4.0f) ? ton : 0.0f;
        float ds = ps - ts, de = pe - te, dc = pc - tc;
        acc += 0.6f * ds * ds + 0.2f * (de * de + dc * dc);
    }

    #pragma unroll
    for (int off = 32; off >= 1; off >>= 1)
        acc += __shfl_down(acc, off, 64);
    if ((tid & 63) == 0) red[tid >> 6] = acc;
    __syncthreads();
    if (tid == 0) {
        float sum = red[0] + red[1] + red[2] + red[3];
        atomicAdd(out, sum * (1.0f / 8388608.0f));  // N = 32*512*512 = 2^23
    }
}

extern "C" void kernel_launch(void* const* d_in, const int* in_sizes, int n_in,
                              void* d_out, int out_size, void* d_ws, size_t ws_size,
                              hipStream_t stream) {
    const float* pred   = (const float*)d_in[0];
    const float* target = (const float*)d_in[1];
    float* out = (float*)d_out;
    hipMemsetAsync(d_out, 0, sizeof(float) * (out_size > 0 ? out_size : 1), stream);
    const int nblocks = 32 * 128;   // 32 images x (16x8) tiles
    skel_conn_loss<<<nblocks, NT, 0, stream>>>(pred, target, out);
}

// Round 3
// 259.058 us; speedup vs baseline: 1.9476x; 1.3591x over previous
//
#include <hip/hip_runtime.h>

// ConnectivityLoss R3: register-resident soft-skeletonize.
// Thread = 8-col x 5-row strip held in VGPRs for all 10 pool passes.
// LDS only for: vertical boundary-row exchange (double-buffered, 1 barrier
// per pass) and final skeleton stash for the epilogue. Horizontal neighbor
// columns via __shfl lane+-1 (lane+-1 == adjacent strip, same rows).

#define IMG 512
#define TW  32            // output tile width  (16 x-tiles)
#define TH  128           // output tile height (4 y-tiles)
#define PW  64            // padded strip-region width (8 strips of 8)
#define XSTRIDE 68        // exchange slot stride (floats) - kills bank degeneracy
#define SKW 34            // skeleton stash: cols [11,44] -> 34
#define SKH 130           // rows [11,140] -> 130
#define NT  256

struct alignas(16) R8 { float v[8]; };

__device__ __forceinline__ float f3min(float a, float b, float c) {
    return fminf(fminf(a, b), c);
}
__device__ __forceinline__ float f3max(float a, float b, float c) {
    return fmaxf(fmaxf(a, b), c);
}

// horizontal 3-tap over an 8-col row; le/ri from neighbor lanes.
template<bool MN>
__device__ __forceinline__ void hrow(const R8& r, float* h) {
    float le = __shfl_up(r.v[7], 1);    // lane s-1's col 8s-1 (s=0: don't-care)
    float ri = __shfl_down(r.v[0], 1);  // lane s+1's col 8s+8 (s=7: don't-care)
    if (MN) {
        h[0] = f3min(le,     r.v[0], r.v[1]);
        h[1] = f3min(r.v[0], r.v[1], r.v[2]);
        h[2] = f3min(r.v[1], r.v[2], r.v[3]);
        h[3] = f3min(r.v[2], r.v[3], r.v[4]);
        h[4] = f3min(r.v[3], r.v[4], r.v[5]);
        h[5] = f3min(r.v[4], r.v[5], r.v[6]);
        h[6] = f3min(r.v[5], r.v[6], r.v[7]);
        h[7] = f3min(r.v[6], r.v[7], ri);
    } else {
        h[0] = f3max(le,     r.v[0], r.v[1]);
        h[1] = f3max(r.v[0], r.v[1], r.v[2]);
        h[2] = f3max(r.v[1], r.v[2], r.v[3]);
        h[3] = f3max(r.v[2], r.v[3], r.v[4]);
        h[4] = f3max(r.v[3], r.v[4], r.v[5]);
        h[5] = f3max(r.v[4], r.v[5], r.v[6]);
        h[6] = f3max(r.v[5], r.v[6], r.v[7]);
        h[7] = f3max(r.v[6], r.v[7], ri);
    }
}

__global__ __launch_bounds__(NT, 2)
void skel_conn_loss(const float* __restrict__ pred,
                    const float* __restrict__ target,
                    float* __restrict__ out)
{
    __shared__ float X[2 * 64 * XSTRIDE];   // exchange, dbuf (34816 B)
    __shared__ float SKP[SKH * SKW];        // pred skeleton (17680 B)
    __shared__ float red[4];
    float* SKT = X;                         // target skeleton aliases dead X

    const int tid = threadIdx.x;
    const int s   = tid & 7;                // strip (8 cols)
    const int g   = tid >> 3;               // row-group (5 rows), 0..31
    const int img = blockIdx.x >> 6;        // 64 tiles per image
    const int rem = blockIdx.x & 63;
    const int ty0 = (rem >> 4) * TH;        // 4 row-tiles
    const int tx0 = (rem & 15) * TW;        // 16 col-tiles

    const int c0  = 8 * s;                  // padded col base
    const int r0  = 5 * g;                  // padded row base
    const int gx0 = tx0 - 12 + c0;          // 16B-aligned (tx0%32==0)
    const bool xin = (tx0 > 0) && (tx0 + TW < IMG);

    R8 A[5], Bv[5];
    int xb = 0;

    #pragma unroll 1
    for (int t = 0; t < 2; ++t) {
        const float* __restrict__ src =
            (t ? target : pred) + (size_t)img * (IMG * IMG);

        // ---- load strip (replicate-clamped at image borders) ----
        #pragma unroll
        for (int i = 0; i < 5; ++i) {
            int gy = min(max(ty0 - 12 + r0 + i, 0), IMG - 1);
            const float* rp = src + gy * IMG;
            if (xin) {
                *(float4*)&A[i].v[0] = *(const float4*)(rp + gx0);
                *(float4*)&A[i].v[4] = *(const float4*)(rp + gx0 + 4);
            } else {
                #pragma unroll
                for (int j = 0; j < 8; ++j) {
                    int gx = min(max(gx0 + j, 0), IMG - 1);
                    A[i].v[j] = rp[gx];
                }
            }
        }

        #pragma unroll 1
        for (int it = 0; it < 5; ++it) {
            // ================= pass 1: Bv = minpool3(A) =================
            {
                float* Xb = X + xb * (64 * XSTRIDE);
                float* pT = Xb + (2 * g) * XSTRIDE + c0;
                float* pB = Xb + (2 * g + 1) * XSTRIDE + c0;
                *(float4*)pT       = *(const float4*)&A[0].v[0];
                *(float4*)(pT + 4) = *(const float4*)&A[0].v[4];
                *(float4*)pB       = *(const float4*)&A[4].v[0];
                *(float4*)(pB + 4) = *(const float4*)&A[4].v[4];
                __syncthreads();
                R8 ab, be;
                if (g > 0) {
                    const float* p = Xb + (2 * g - 1) * XSTRIDE + c0;
                    *(float4*)&ab.v[0] = *(const float4*)p;
                    *(float4*)&ab.v[4] = *(const float4*)(p + 4);
                } else ab = A[0];          // tile edge: finite garbage
                if (g < 31) {
                    const float* p = Xb + (2 * g + 2) * XSTRIDE + c0;
                    *(float4*)&be.v[0] = *(const float4*)p;
                    *(float4*)&be.v[4] = *(const float4*)(p + 4);
                } else be = A[4];
                float w0[8], w1[8], w2[8];
                hrow<true>(ab,   w0);
                hrow<true>(A[0], w1);
                hrow<true>(A[1], w2);
                #pragma unroll
                for (int j = 0; j < 8; ++j) Bv[0].v[j] = f3min(w0[j], w1[j], w2[j]);
                hrow<true>(A[2], w0);
                #pragma unroll
                for (int j = 0; j < 8; ++j) Bv[1].v[j] = f3min(w1[j], w2[j], w0[j]);
                hrow<true>(A[3], w1);
                #pragma unroll
                for (int j = 0; j < 8; ++j) Bv[2].v[j] = f3min(w2[j], w0[j], w1[j]);
                hrow<true>(A[4], w2);
                #pragma unroll
                for (int j = 0; j < 8; ++j) Bv[3].v[j] = f3min(w0[j], w1[j], w2[j]);
                hrow<true>(be,   w0);
                #pragma unroll
                for (int j = 0; j < 8; ++j) Bv[4].v[j] = f3min(w1[j], w2[j], w0[j]);
                xb ^= 1;
            }
            // ====== pass 2: A = relu(A - relu(maxpool3(Bv) - Bv)) ======
            {
                float* Xb = X + xb * (64 * XSTRIDE);
                float* pT = Xb + (2 * g) * XSTRIDE + c0;
                float* pB = Xb + (2 * g + 1) * XSTRIDE + c0;
                *(float4*)pT       = *(const float4*)&Bv[0].v[0];
                *(float4*)(pT + 4) = *(const float4*)&Bv[0].v[4];
                *(float4*)pB       = *(const float4*)&Bv[4].v[0];
                *(float4*)(pB + 4) = *(const float4*)&Bv[4].v[4];
                __syncthreads();
                R8 ab, be;
                if (g > 0) {
                    const float* p = Xb + (2 * g - 1) * XSTRIDE + c0;
                    *(float4*)&ab.v[0] = *(const float4*)p;
                    *(float4*)&ab.v[4] = *(const float4*)(p + 4);
                } else ab = Bv[0];
                if (g < 31) {
                    const float* p = Xb + (2 * g + 2) * XSTRIDE + c0;
                    *(float4*)&be.v[0] = *(const float4*)p;
                    *(float4*)&be.v[4] = *(const float4*)(p + 4);
                } else be = Bv[4];
                float w0[8], w1[8], w2[8];
                #define UPD(i, a, b, c)                                        \
                    _Pragma("unroll")                                          \
                    for (int j = 0; j < 8; ++j) {                              \
                        float mx = f3max((a)[j], (b)[j], (c)[j]);              \
                        float ct = fmaxf(mx - Bv[i].v[j], 0.0f);               \
                        A[i].v[j] = fmaxf(A[i].v[j] - ct, 0.0f);               \
                    }
                hrow<false>(ab,    w0);
                hrow<false>(Bv[0], w1);
                hrow<false>(Bv[1], w2);
                UPD(0, w0, w1, w2)
                hrow<false>(Bv[2], w0);
                UPD(1, w1, w2, w0)
                hrow<false>(Bv[3], w1);
                UPD(2, w2, w0, w1)
                hrow<false>(Bv[4], w2);
                UPD(3, w0, w1, w2)
                hrow<false>(be,    w0);
                UPD(4, w1, w2, w0)
                #undef UPD
                xb ^= 1;
            }
        }

        // ---- stash skeleton consumed region to LDS ----
        __syncthreads();                    // all X reads done (SKT aliases X)
        {
            float* SK = t ? SKT : SKP;
            #pragma unroll
            for (int i = 0; i < 5; ++i) {
                int pr = r0 + i;
                if (pr >= 11 && pr <= 140) {
                    #pragma unroll
                    for (int j = 0; j < 8; ++j) {
                        int pc = c0 + j;
                        if (pc >= 11 && pc <= 44)
                            SK[(pr - 11) * SKW + (pc - 11)] = A[i].v[j];
                    }
                }
            }
        }
        __syncthreads();
    }

    // ---- epilogue: sumpool3 + indicators + weighted squared diff ----
    float acc = 0.0f;
    #pragma unroll 1
    for (int k = 0; k < 16; ++k) {
        int e  = k * NT + tid;              // 0..4095
        int ly = e >> 5, lx = e & 31;
        int gy = ty0 + ly, gx = tx0 + lx;
        int base = (ly + 1) * SKW + (lx + 1);
        float ps = SKP[base], ts = SKT[base];
        float pn = 0.0f, tn = 0.0f;
        #pragma unroll
        for (int dy = -1; dy <= 1; ++dy) {
            if ((unsigned)(gy + dy) >= IMG) continue;
            #pragma unroll
            for (int dx = -1; dx <= 1; ++dx) {
                if ((unsigned)(gx + dx) >= IMG) continue;
                int o = base + dy * SKW + dx;
                pn += SKP[o];
                tn += SKT[o];
            }
        }
        float pon = (ps > 0.5f) ? 1.0f : 0.0f;
        float ton = (ts > 0.5f) ? 1.0f : 0.0f;
        float pe = (pn == 2.0f) ? pon : 0.0f;
        float te = (tn == 2.0f) ? ton : 0.0f;
        float pc = (pn >= 4.0f) ? pon : 0.0f;
        float tc = (tn >= 4.0f) ? ton : 0.0f;
        float ds = ps - ts, de = pe - te, dc = pc - tc;
        acc += 0.6f * ds * ds + 0.2f * (de * de + dc * dc);
    }

    #pragma unroll
    for (int off = 32; off >= 1; off >>= 1)
        acc += __shfl_down(acc, off, 64);
    if ((tid & 63) == 0) red[tid >> 6] = acc;
    __syncthreads();
    if (tid == 0) {
        float sum = red[0] + red[1] + red[2] + red[3];
        atomicAdd(out, sum * (1.0f / 8388608.0f));  // N = 32*512*512 = 2^23
    }
}

extern "C" void kernel_launch(void* const* d_in, const int* in_sizes, int n_in,
                              void* d_out, int out_size, void* d_ws, size_t ws_size,
                              hipStream_t stream) {
    const float* pred   = (const float*)d_in[0];
    const float* target = (const float*)d_in[1];
    float* out = (float*)d_out;
    hipMemsetAsync(d_out, 0, sizeof(float) * (out_size > 0 ? out_size : 1), stream);
    const int nblocks = 32 * 64;   // 32 images x (4x16) tiles
    skel_conn_loss<<<nblocks, NT, 0, stream>>>(pred, target, out);
}